// Round 3
// baseline (880.327 us; speedup 1.0000x reference)
//
#include <hip/hip_runtime.h>

// CrossScaleAttention on MI355X — round 8.
// R7 post-mortem: counted-vmcnt barrier + setprio + Ln-LDS all NEUTRAL
// (452 vs 448us) -> stall insensitive to sync structure. Revised theory:
// per-CU L2 line-fill throughput (MLP) bound. Per block-iter the V tile
// [96x576]=110.6KB is read regardless of BM -> ~3456 lines/CU/iter-round;
// at ~300cy L2 latency and ~64 outstanding line-fills/CU -> ~16Kcy/slot,
// matching the measured ~10Kcy. Lever = fewer lines per query, i.e. MORE
// QUERIES PER BLOCK. R8: BM=64 (4 py-rows x 16px), 4-wave blocks:
//   score: wave w owns 16-q tile w, both 48-key halves (2x27 MFMA)
//   PV: wave w owns n-quarter w: P[64,96]@V[96,144] -> acc[4][9] (144 AGPR)
// Grid halves (nb*144): V + Ks line traffic per CU halves. v1 prefetch
// dropped for regs (~250 total); ks1/ks2 V reloaded per-nt after last use
// (covered by remaining 32 MFMAs of the phase). kgather: 2 q-rows/block
// (3 staged rows vs 2x2) -> -25% Z reads, half the blocks.
//
// Workspace (101,246,976 B; known-good >= 105.6 MB):
//   xf16 : [4][98][98][32] fp16 match_input, zero halo        2,458,624
//   rkl  : [4][50][50][32] fp16 ref, zero halo                  640,000
//   ef32 : [4][50][50][64] f32 embed_w, zero halo             2,560,000
//   vtp  : [4][576][2304] bf16 V^T (n=tap*64+c, l=ly*48+lx)  10,616,832
//   invn : [4][2304] f32 10/max(norm,1e-4)                       36,864
//   Z    : [nb][9216][576] f32                            nb*21,233,664

typedef unsigned short u16;
typedef __attribute__((ext_vector_type(8))) short short8;      // 8 bf16
typedef __attribute__((ext_vector_type(8))) _Float16 half8;    // 8 fp16
typedef __attribute__((ext_vector_type(4))) float f32x4;

__device__ __forceinline__ u16 f2bf(float f) {
    unsigned u = __float_as_uint(f);
    unsigned r = (u + 0x7FFFu + ((u >> 16) & 1u)) >> 16;   // RNE
    return (u16)r;
}
__device__ __forceinline__ float bf2f(u16 h) {
    return __uint_as_float(((unsigned)h) << 16);
}
__device__ __forceinline__ u16 f2h(float f) {
    _Float16 h = (_Float16)f;           // v_cvt_f16_f32 (RNE)
    u16 u; __builtin_memcpy(&u, &h, 2); return u;
}
__device__ __forceinline__ float h2f(u16 u) {
    _Float16 h; __builtin_memcpy(&h, &u, 2); return (float)h;
}

// ---------------------------------------------------------------- zero fill
__global__ void kzero(float4* p, long n) {
    long i = (long)blockIdx.x * blockDim.x + threadIdx.x;
    long st = (long)gridDim.x * blockDim.x;
    float4 z; z.x = 0.f; z.y = 0.f; z.z = 0.f; z.w = 0.f;
    for (; i < n; i += st) p[i] = z;
}

// ------------------------------------------------- match_input -> xf16
__global__ void kmatch(const float* __restrict__ input, const float* __restrict__ w1,
                       const float* __restrict__ b1, const float* __restrict__ a1,
                       u16* __restrict__ xf16) {
    __shared__ float xl[64 * 96];
    __shared__ float wl[32 * 65];
    int b = blockIdx.x / 96, y = blockIdx.x % 96;
    int tid = threadIdx.x;
    for (int i = tid; i < 64 * 96; i += 256) {
        int ci = i / 96, xx = i % 96;
        xl[i] = input[(((b * 64 + ci) * 96) + y) * 96 + xx];
    }
    for (int i = tid; i < 2048; i += 256) wl[(i >> 6) * 65 + (i & 63)] = w1[i];
    __syncthreads();
    float aa = a1[0];
    for (int o = tid; o < 96 * 32; o += 256) {
        int xx = o >> 5, c = o & 31;
        float acc = b1[c];
        #pragma unroll
        for (int ci = 0; ci < 64; ci++) acc = fmaf(xl[ci * 96 + xx], wl[c * 65 + ci], acc);
        float v = acc >= 0.f ? acc : aa * acc;
        xf16[((b * 98 + y + 1) * 98 + (xx + 1)) * 32 + c] = f2h(v);
    }
}

// --------------------- small -> ef32 (embed, f32) + rkl fp16 (ref)
__global__ void ksmall(const float* __restrict__ small, const float* __restrict__ wasm,
                       const float* __restrict__ basm, const float* __restrict__ aasm,
                       const float* __restrict__ wm2, const float* __restrict__ bm2,
                       const float* __restrict__ am2,
                       float* __restrict__ ef32, u16* __restrict__ rkl) {
    __shared__ float sl[64 * 48];
    __shared__ float wa[64 * 65];
    __shared__ float wm[32 * 65];
    int b = blockIdx.x / 48, y = blockIdx.x % 48;
    int tid = threadIdx.x;
    for (int i = tid; i < 64 * 48; i += 256) {
        int ci = i / 48, xx = i % 48;
        sl[i] = small[(((b * 64 + ci) * 48) + y) * 48 + xx];
    }
    for (int i = tid; i < 4096; i += 256) wa[(i >> 6) * 65 + (i & 63)] = wasm[i];
    for (int i = tid; i < 2048; i += 256) wm[(i >> 6) * 65 + (i & 63)] = wm2[i];
    __syncthreads();
    float ae = aasm[0], ar = am2[0];
    for (int o = tid; o < 48 * 64; o += 256) {            // embed_w
        int xx = o >> 6, c = o & 63;
        float acc = basm[c];
        #pragma unroll
        for (int ci = 0; ci < 64; ci++) acc = fmaf(sl[ci * 48 + xx], wa[c * 65 + ci], acc);
        float v = acc >= 0.f ? acc : ae * acc;
        ef32[((b * 50 + y + 1) * 50 + (xx + 1)) * 64 + c] = v;
    }
    for (int o = tid; o < 48 * 32; o += 256) {            // ref -> rkl fp16
        int xx = o >> 5, c = o & 31;
        float acc = bm2[c];
        #pragma unroll
        for (int ci = 0; ci < 64; ci++) acc = fmaf(sl[ci * 48 + xx], wm[c * 65 + ci], acc);
        float v = acc >= 0.f ? acc : ar * acc;
        rkl[((b * 50 + y + 1) * 50 + (xx + 1)) * 32 + c] = f2h(v);
    }
}

// ------------------------------------------------------------ invnorm per key
__global__ void kinvnorm(const u16* __restrict__ rkl, float* __restrict__ invn) {
    int idx = blockIdx.x * 256 + threadIdx.x;   // 9216 exact
    int b = idx / 2304, l = idx % 2304;
    int ly = l / 48, lx = l % 48;
    float s = 0.f;
    for (int ty = 0; ty < 3; ty++)
        for (int tx = 0; tx < 3; tx++) {
            int base = ((b * 50 + ly + ty) * 50 + (lx + tx)) * 32;
            #pragma unroll
            for (int c = 0; c < 32; c++) {
                float v = h2f(rkl[base + c]);
                s = fmaf(v, v, s);
            }
        }
    invn[idx] = 10.f / fmaxf(sqrtf(s), 1e-4f);   // SCALE folded in
}

// ------------------------------------------------------------- pack V^T bf16
__global__ void kvtp(const float* __restrict__ ef32, u16* __restrict__ vtp) {
    int bi = blockIdx.x;
    int b = bi / 576, n = bi % 576;
    int t = n >> 6, c = n & 63;
    int ty = t / 3, tx = t % 3;
    const float* eb = ef32 + (size_t)b * 50 * 50 * 64 + c;
    u16* vo = vtp + (size_t)(b * 576 + n) * 2304;
    for (int l = threadIdx.x; l < 2304; l += 256) {
        int ly = l / 48, lx = l - ly * 48;
        vo[l] = f2bf(eb[((ly + ty) * 50 + (lx + tx)) * 64]);
    }
}

// ---------------------------------------------- async Ks staging (12800 B)
__device__ __forceinline__ void stage_ks(const u16* __restrict__ src, u16* dst, int tid) {
    int wb = tid & ~63;   // wave-uniform LDS base
    #pragma unroll
    for (int k = 0; k < 3; ++k)
        __builtin_amdgcn_global_load_lds(
            (const __attribute__((address_space(1))) void*)(src + (size_t)(tid + k * 256) * 8),
            (__attribute__((address_space(3))) void*)(dst + (size_t)(wb + k * 256) * 8),
            16, 0, 0);
    if (tid < 32)   // tail: 800*16B total, lanes 0..31 of wave 0
        __builtin_amdgcn_global_load_lds(
            (const __attribute__((address_space(1))) void*)(src + (size_t)(tid + 768) * 8),
            (__attribute__((address_space(3))) void*)(dst + (size_t)768 * 8),
            16, 0, 0);
}

// ------------------------------------------------------------- fused score+PV
// grid = nb*144; block = 256 (4 waves). BM=64 queries (4 py-rows x 16 px),
// BN=96 keys/iter, 24 iters. Wave w: score for q-tile w (both key halves),
// PV for n-quarter w over all 64 q (acc[4][9], 144 AGPR). One counted-vmcnt
// barrier per iter (vmcnt(9): drains Ks DMA, keeps 9 V loads in flight).
__launch_bounds__(256, 2)
__global__ void kfused3(const u16* __restrict__ xf16, const u16* __restrict__ rkl,
                        const u16* __restrict__ vtp, const float* __restrict__ invn,
                        float* __restrict__ Z, int b0, int nb) {
    __shared__ u16 Ks[2][6400];     // 25600 B: dbuf, 4 halo rows x [50 px][32 c] fp16
    __shared__ u16 Pl[2][6144];     // 24576 B: dbuf, [4 mtile][3 kb][16 m][32 kc]
    __shared__ float Ln[2304];      //  9216 B: invn for this batch
    __shared__ float llds[4][16];   //   256 B  -> 59648 B total

    int tid = threadIdx.x;
    int w = tid >> 6, lane = tid & 63, l15 = lane & 15, quad = lane >> 4;
    int bi = blockIdx.x, brel, t;
    if (nb == 4) { brel = bi & 3; t = bi >> 2; }   // bi%8 fixes XCD: 1 batch per XCD
    else         { brel = 0; t = bi; }
    int b = b0 + brel;
    int px0 = (t % 6) * 16, pyb = (t / 6) * 4;     // 6 x-tiles x 24 y-groups = 144

    const u16* xb = xf16 + (size_t)b * 98 * 98 * 32;
    const u16* rb = rkl + (size_t)b * 50 * 50 * 32;
    const float* invb = invn + b * 2304;
    const u16* vw = vtp + (size_t)b * 576 * 2304 + (size_t)(w * 144 + l15) * 2304 + quad * 8;

    stage_ks(rb, Ks[0], tid);       // async; drained by the prologue barrier
    __builtin_amdgcn_sched_barrier(0);

    // invn -> LDS (once)
    for (int i = tid; i < 576; i += 256)
        ((float4*)Ln)[i] = ((const float4*)invb)[i];

    // Q fragments for this wave's 16-q tile (py row pyb+w), in registers
    half8 qf[3][3];
    #pragma unroll
    for (int ty = 0; ty < 3; ++ty)
        #pragma unroll
        for (int tx = 0; tx < 3; ++tx)
            qf[ty][tx] = *(const half8*)(xb + (((pyb + w + ty) * 98) + (px0 + l15 + tx)) * 32 + quad * 8);

    f32x4 acc[36];
    #pragma unroll
    for (int i = 0; i < 36; i++) acc[i] = (f32x4)0.f;
    float lacc[4] = {0.f, 0.f, 0.f, 0.f};

    __syncthreads();   // prologue: full drain (Ks[0] DMA + Ln staged)

    short8 vv[9];

    for (int it = 0; it < 24; ++it) {
        int ly0 = it * 2;
        int cur = it & 1;

        // ---- 1. DMA next Ks (oldest VMEM of this iter — vmcnt(9) relies on it)
        if (it < 23) stage_ks(rb + (ly0 + 2) * 1600, Ks[cur ^ 1], tid);
        __builtin_amdgcn_sched_barrier(0);   // pin DMA-first issue order

        // ---- 2. V ks=0 loads (9; ride across the barrier into PV)
        const u16* vit = vw + it * 96;
        #pragma unroll
        for (int nt = 0; nt < 9; ++nt) vv[nt] = *(const short8*)(vit + (size_t)nt * 36864);

        // ---- 3+4. score + exp for both key halves of this wave's q-tile
        const u16* Kc = Ks[cur];
        u16* Pc = Pl[cur];
        #pragma unroll
        for (int kh = 0; kh < 2; ++kh) {
            f32x4 sf[3];
            #pragma unroll
            for (int i = 0; i < 3; i++) sf[i] = (f32x4)0.f;
            __builtin_amdgcn_s_setprio(1);
            #pragma unroll
            for (int ty = 0; ty < 3; ++ty)
                #pragma unroll
                for (int tx = 0; tx < 3; ++tx) {
                    half8 a = qf[ty][tx];
                    #pragma unroll
                    for (int lxo = 0; lxo < 3; ++lxo) {
                        half8 bb = *(const half8*)&Kc[(kh + ty) * 1600 + (lxo * 16 + l15 + tx) * 32 + quad * 8];
                        sf[lxo] = __builtin_amdgcn_mfma_f32_16x16x32_f16(a, bb, sf[lxo], 0, 0, 0);
                    }
                }
            __builtin_amdgcn_s_setprio(0);
            #pragma unroll
            for (int lxo = 0; lxo < 3; ++lxo) {
                float invs = Ln[(ly0 + kh) * 48 + lxo * 16 + l15];
                int k = kh * 48 + lxo * 16 + l15;
                int kb = k >> 5;
                int kc = (k & 31) ^ (quad << 3);   // XOR swizzle by quad (= m>>2)
                #pragma unroll
                for (int r = 0; r < 4; ++r) {
                    float p = __expf(sf[lxo][r] * invs);
                    u16 h = f2bf(p);
                    Pc[(w * 3 + kb) * 512 + (quad * 4 + r) * 32 + kc] = h;
                    lacc[r] += bf2f(h);   // l exactly as the PV MFMA sees P
                }
            }
        }

        // ---- 5. counted-vmcnt barrier: Pl visible (lgkm 0) + Ks DMA landed
        // (vmcnt<=9: the 9 newer vv loads may stay in flight).
        asm volatile("s_waitcnt vmcnt(9) lgkmcnt(0)" ::: "memory");
        __builtin_amdgcn_s_barrier();
        __builtin_amdgcn_sched_barrier(0);

        // ---- 6. PV: O[64, this wave's 144 cols] += P[64,96] @ V[96,144], bf16
        const u16* Pr = Pl[cur];
        __builtin_amdgcn_s_setprio(1);
        #pragma unroll
        for (int ks = 0; ks < 3; ++ks) {
            short8 pa0 = *(const short8*)&Pr[(0 * 3 + ks) * 512 + l15 * 32 + ((quad ^ (l15 >> 2)) & 3) * 8];
            short8 pa1 = *(const short8*)&Pr[(1 * 3 + ks) * 512 + l15 * 32 + ((quad ^ (l15 >> 2)) & 3) * 8];
            short8 pa2 = *(const short8*)&Pr[(2 * 3 + ks) * 512 + l15 * 32 + ((quad ^ (l15 >> 2)) & 3) * 8];
            short8 pa3 = *(const short8*)&Pr[(3 * 3 + ks) * 512 + l15 * 32 + ((quad ^ (l15 >> 2)) & 3) * 8];
            #pragma unroll
            for (int nt = 0; nt < 9; ++nt) {
                short8 vn = vv[nt];
                acc[0 * 9 + nt] = __builtin_amdgcn_mfma_f32_16x16x32_bf16(pa0, vn, acc[0 * 9 + nt], 0, 0, 0);
                acc[1 * 9 + nt] = __builtin_amdgcn_mfma_f32_16x16x32_bf16(pa1, vn, acc[1 * 9 + nt], 0, 0, 0);
                acc[2 * 9 + nt] = __builtin_amdgcn_mfma_f32_16x16x32_bf16(pa2, vn, acc[2 * 9 + nt], 0, 0, 0);
                acc[3 * 9 + nt] = __builtin_amdgcn_mfma_f32_16x16x32_bf16(pa3, vn, acc[3 * 9 + nt], 0, 0, 0);
                if (ks < 2)   // reload right after last use; covered by rest of phase
                    vv[nt] = *(const short8*)(vit + (size_t)nt * 36864 + (ks + 1) * 32);
            }
        }
        __builtin_amdgcn_s_setprio(0);
    }

    // ---- epilogue: reduce l over l15; share per-tile l via LDS; Z = O/(6l)
    #pragma unroll
    for (int r = 0; r < 4; ++r) {
        float v = lacc[r];
        v += __shfl_xor(v, 1);
        v += __shfl_xor(v, 2);
        v += __shfl_xor(v, 4);
        v += __shfl_xor(v, 8);
        lacc[r] = v;
    }
    if (l15 == 0) {
        #pragma unroll
        for (int r = 0; r < 4; ++r)
            llds[w][quad * 4 + r] = lacc[r];
    }
    __syncthreads();
    float* Zb = Z + (size_t)brel * 9216 * 576;
    #pragma unroll
    for (int mt = 0; mt < 4; ++mt) {
        #pragma unroll
        for (int r = 0; r < 4; ++r) {
            int q = (pyb + mt) * 96 + px0 + quad * 4 + r;
            float rl = 1.0f / (llds[mt][quad * 4 + r] * 6.0f);
            float* zr = Zb + (size_t)q * 576 + w * 144;
            #pragma unroll
            for (int nt = 0; nt < 9; ++nt)
                __builtin_nontemporal_store(acc[mt * 9 + nt][r] * rl, zr + nt * 16 + l15);
        }
    }
}

// ------------------------------------------------------------- gather (Z -> out)
// 2 q-rows per block: stage 3 py rows (vs 2x2), -25% Z reads, half the blocks.
__global__ void kgather(const float* __restrict__ Z, float* __restrict__ out, int b0) {
    __shared__ float zb[3 * 9 * 580];   // 62640 B
    int bi = blockIdx.x;                // nb*48*12
    int brel = bi / (48 * 12);
    int rem = bi % (48 * 12);
    int b = b0 + brel;
    int j = rem / 12, xt = rem % 12;
    int q0 = 2 * j;
    int ox0 = xt * 16, p0 = ox0 >> 1;
    const float* Zb = Z + (size_t)brel * 9216 * 576;
    int tid = threadIdx.x;
    for (int id = tid; id < 3888; id += 256) {
        int pi = id / 1296, r2 = id % 1296;
        int pxi = r2 / 144, n4 = r2 % 144;
        int py = q0 + pi; if (py > 95) py = 95;
        int px = p0 + pxi; if (px > 95) px = 95;
        *(float4*)&zb[(pi * 9 + pxi) * 580 + n4 * 4] =
            *(const float4*)&Zb[(size_t)(py * 96 + px) * 576 + n4 * 4];
    }
    __syncthreads();
    int xi = tid & 15, cq = tid >> 4;
    int ox = ox0 + xi;
    bool oxv = ox <= 190;
    int ntx, txl[2], pxl[2];
    if (xi & 1) { ntx = 2; txl[0] = 0; pxl[0] = (xi + 1) >> 1; txl[1] = 2; pxl[1] = (xi - 1) >> 1; }
    else        { ntx = 1; txl[0] = 1; pxl[0] = xi >> 1; txl[1] = 1; pxl[1] = xi >> 1; }
    #pragma unroll
    for (int sq = 0; sq < 2; ++sq) {
        int q = q0 + sq;
        int oy0 = 2 * q;
        #pragma unroll
        for (int ck = 0; ck < 4; ++ck) {
            int c = cq + ck * 16;
            float v0 = 0.f, v1 = 0.f;
            for (int jj = 0; jj < ntx; ++jj) {
                int tx = txl[jj], pxi = pxl[jj];
                v0 += zb[((sq + 0) * 9 + pxi) * 580 + (3 + tx) * 64 + c];
                v1 += zb[((sq + 1) * 9 + pxi) * 580 + (0 + tx) * 64 + c];
                v1 += zb[((sq + 0) * 9 + pxi) * 580 + (6 + tx) * 64 + c];
            }
            if (oxv) {
                float* o = out + (((size_t)(b * 64 + c) * 191 + oy0) * 191 + ox);
                *o = v0;
                if (q < 95) *(o + 191) = v1;
            }
        }
    }
}

// --------------------------------------------------------------------- host
extern "C" void kernel_launch(void* const* d_in, const int* in_sizes, int n_in,
                              void* d_out, int out_size, void* d_ws, size_t ws_size,
                              hipStream_t stream) {
    const float* input = (const float*)d_in[0];
    const float* small = (const float*)d_in[1];
    const float* w1 = (const float*)d_in[2];
    const float* b1 = (const float*)d_in[3];
    const float* a1 = (const float*)d_in[4];
    const float* w2 = (const float*)d_in[5];
    const float* b2 = (const float*)d_in[6];
    const float* a2 = (const float*)d_in[7];
    const float* wa = (const float*)d_in[8];
    const float* ba = (const float*)d_in[9];
    const float* aa = (const float*)d_in[10];

    char* ws = (char*)d_ws;
    u16* xf16 = (u16*)(ws + 0);             //  2,458,624
    u16* rkl = (u16*)(ws + 2458624);        //    640,000
    float* ef = (float*)(ws + 3098624);     //  2,560,000
    u16* vtp = (u16*)(ws + 5658624);        // 10,616,832
    float* invn = (float*)(ws + 16275456);  //     36,864
    const size_t PREP = 16312320;
    float* Zbuf = (float*)(ws + PREP);      // nb*21,233,664
    float* out = (float*)d_out;

    int nb = (ws_size >= (size_t)101246976) ? 4 : 1;

    kzero<<<1024, 256, 0, stream>>>((float4*)ws, 5658624 / 16);   // halo'd arrays
    kmatch<<<384, 256, 0, stream>>>(input, w1, b1, a1, xf16);
    ksmall<<<192, 256, 0, stream>>>(small, wa, ba, aa, w2, b2, a2, ef, rkl);
    kinvnorm<<<36, 256, 0, stream>>>(rkl, invn);
    kvtp<<<2304, 256, 0, stream>>>(ef, vtp);

    for (int b0 = 0; b0 < 4; b0 += nb) {
        kfused3<<<nb * 144, 256, 0, stream>>>(xf16, rkl, vtp, invn, Zbuf, b0, nb);
        kgather<<<nb * 576, 256, 0, stream>>>(Zbuf, out, b0);
    }
}

// Round 4
// 540.629 us; speedup vs baseline: 1.6283x; 1.6283x over previous
//
#include <hip/hip_runtime.h>

// CrossScaleAttention on MI355X — round 9.
// R8 post-mortem: FETCH 12->468MB, WRITE 94->544MB = ~1GB scratch SPILL
// traffic (144 AGPR + 128 VGPR = 272 > 256 unified budget at 2 waves/SIMD).
// BM=64 line-demand theory never tested — confounded. R9 = spill-free BM=64:
//   (1) Q fragments -> LDS (Qs[6][18][32] fp16, 6.9KB, staged once): -36 VGPR;
//       score reads are contiguous conflict-free ds_read_b128.
//   (2) PV pa operands loaded in 2x2 halves (8 regs not 16): -8 VGPR.
//   (3) kgather reverted to proven R7 2-row version (remove confound).
// Unified estimate ~240-254 <= 256 -> no spill. LDS 66.6KB -> 2 blocks/CU.
// Pre-committed reads: FETCH~13MB & ~300us => V-traffic theory confirmed;
// FETCH~13MB & ~450us => theory dead, ablation probe next; FETCH high =>
// still spilling, revert R6.
//
// Workspace (101,246,976 B; known-good >= 105.6 MB):
//   xf16 : [4][98][98][32] fp16 match_input, zero halo        2,458,624
//   rkl  : [4][50][50][32] fp16 ref, zero halo                  640,000
//   ef32 : [4][50][50][64] f32 embed_w, zero halo             2,560,000
//   vtp  : [4][576][2304] bf16 V^T (n=tap*64+c, l=ly*48+lx)  10,616,832
//   invn : [4][2304] f32 10/max(norm,1e-4)                       36,864
//   Z    : [nb][9216][576] f32                            nb*21,233,664

typedef unsigned short u16;
typedef __attribute__((ext_vector_type(8))) short short8;      // 8 bf16
typedef __attribute__((ext_vector_type(8))) _Float16 half8;    // 8 fp16
typedef __attribute__((ext_vector_type(4))) float f32x4;

__device__ __forceinline__ u16 f2bf(float f) {
    unsigned u = __float_as_uint(f);
    unsigned r = (u + 0x7FFFu + ((u >> 16) & 1u)) >> 16;   // RNE
    return (u16)r;
}
__device__ __forceinline__ float bf2f(u16 h) {
    return __uint_as_float(((unsigned)h) << 16);
}
__device__ __forceinline__ u16 f2h(float f) {
    _Float16 h = (_Float16)f;           // v_cvt_f16_f32 (RNE)
    u16 u; __builtin_memcpy(&u, &h, 2); return u;
}
__device__ __forceinline__ float h2f(u16 u) {
    _Float16 h; __builtin_memcpy(&h, &u, 2); return (float)h;
}

// ---------------------------------------------------------------- zero fill
__global__ void kzero(float4* p, long n) {
    long i = (long)blockIdx.x * blockDim.x + threadIdx.x;
    long st = (long)gridDim.x * blockDim.x;
    float4 z; z.x = 0.f; z.y = 0.f; z.z = 0.f; z.w = 0.f;
    for (; i < n; i += st) p[i] = z;
}

// ------------------------------------------------- match_input -> xf16
__global__ void kmatch(const float* __restrict__ input, const float* __restrict__ w1,
                       const float* __restrict__ b1, const float* __restrict__ a1,
                       u16* __restrict__ xf16) {
    __shared__ float xl[64 * 96];
    __shared__ float wl[32 * 65];
    int b = blockIdx.x / 96, y = blockIdx.x % 96;
    int tid = threadIdx.x;
    for (int i = tid; i < 64 * 96; i += 256) {
        int ci = i / 96, xx = i % 96;
        xl[i] = input[(((b * 64 + ci) * 96) + y) * 96 + xx];
    }
    for (int i = tid; i < 2048; i += 256) wl[(i >> 6) * 65 + (i & 63)] = w1[i];
    __syncthreads();
    float aa = a1[0];
    for (int o = tid; o < 96 * 32; o += 256) {
        int xx = o >> 5, c = o & 31;
        float acc = b1[c];
        #pragma unroll
        for (int ci = 0; ci < 64; ci++) acc = fmaf(xl[ci * 96 + xx], wl[c * 65 + ci], acc);
        float v = acc >= 0.f ? acc : aa * acc;
        xf16[((b * 98 + y + 1) * 98 + (xx + 1)) * 32 + c] = f2h(v);
    }
}

// --------------------- small -> ef32 (embed, f32) + rkl fp16 (ref)
__global__ void ksmall(const float* __restrict__ small, const float* __restrict__ wasm,
                       const float* __restrict__ basm, const float* __restrict__ aasm,
                       const float* __restrict__ wm2, const float* __restrict__ bm2,
                       const float* __restrict__ am2,
                       float* __restrict__ ef32, u16* __restrict__ rkl) {
    __shared__ float sl[64 * 48];
    __shared__ float wa[64 * 65];
    __shared__ float wm[32 * 65];
    int b = blockIdx.x / 48, y = blockIdx.x % 48;
    int tid = threadIdx.x;
    for (int i = tid; i < 64 * 48; i += 256) {
        int ci = i / 48, xx = i % 48;
        sl[i] = small[(((b * 64 + ci) * 48) + y) * 48 + xx];
    }
    for (int i = tid; i < 4096; i += 256) wa[(i >> 6) * 65 + (i & 63)] = wasm[i];
    for (int i = tid; i < 2048; i += 256) wm[(i >> 6) * 65 + (i & 63)] = wm2[i];
    __syncthreads();
    float ae = aasm[0], ar = am2[0];
    for (int o = tid; o < 48 * 64; o += 256) {            // embed_w
        int xx = o >> 6, c = o & 63;
        float acc = basm[c];
        #pragma unroll
        for (int ci = 0; ci < 64; ci++) acc = fmaf(sl[ci * 48 + xx], wa[c * 65 + ci], acc);
        float v = acc >= 0.f ? acc : ae * acc;
        ef32[((b * 50 + y + 1) * 50 + (xx + 1)) * 64 + c] = v;
    }
    for (int o = tid; o < 48 * 32; o += 256) {            // ref -> rkl fp16
        int xx = o >> 5, c = o & 31;
        float acc = bm2[c];
        #pragma unroll
        for (int ci = 0; ci < 64; ci++) acc = fmaf(sl[ci * 48 + xx], wm[c * 65 + ci], acc);
        float v = acc >= 0.f ? acc : ar * acc;
        rkl[((b * 50 + y + 1) * 50 + (xx + 1)) * 32 + c] = f2h(v);
    }
}

// ------------------------------------------------------------ invnorm per key
__global__ void kinvnorm(const u16* __restrict__ rkl, float* __restrict__ invn) {
    int idx = blockIdx.x * 256 + threadIdx.x;   // 9216 exact
    int b = idx / 2304, l = idx % 2304;
    int ly = l / 48, lx = l % 48;
    float s = 0.f;
    for (int ty = 0; ty < 3; ty++)
        for (int tx = 0; tx < 3; tx++) {
            int base = ((b * 50 + ly + ty) * 50 + (lx + tx)) * 32;
            #pragma unroll
            for (int c = 0; c < 32; c++) {
                float v = h2f(rkl[base + c]);
                s = fmaf(v, v, s);
            }
        }
    invn[idx] = 10.f / fmaxf(sqrtf(s), 1e-4f);   // SCALE folded in
}

// ------------------------------------------------------------- pack V^T bf16
__global__ void kvtp(const float* __restrict__ ef32, u16* __restrict__ vtp) {
    int bi = blockIdx.x;
    int b = bi / 576, n = bi % 576;
    int t = n >> 6, c = n & 63;
    int ty = t / 3, tx = t % 3;
    const float* eb = ef32 + (size_t)b * 50 * 50 * 64 + c;
    u16* vo = vtp + (size_t)(b * 576 + n) * 2304;
    for (int l = threadIdx.x; l < 2304; l += 256) {
        int ly = l / 48, lx = l - ly * 48;
        vo[l] = f2bf(eb[((ly + ty) * 50 + (lx + tx)) * 64]);
    }
}

// ---------------------------------------------- async Ks staging (12800 B)
__device__ __forceinline__ void stage_ks(const u16* __restrict__ src, u16* dst, int tid) {
    int wb = tid & ~63;   // wave-uniform LDS base
    #pragma unroll
    for (int k = 0; k < 3; ++k)
        __builtin_amdgcn_global_load_lds(
            (const __attribute__((address_space(1))) void*)(src + (size_t)(tid + k * 256) * 8),
            (__attribute__((address_space(3))) void*)(dst + (size_t)(wb + k * 256) * 8),
            16, 0, 0);
    if (tid < 32)   // tail: 800*16B total, lanes 0..31 of wave 0
        __builtin_amdgcn_global_load_lds(
            (const __attribute__((address_space(1))) void*)(src + (size_t)(tid + 768) * 8),
            (__attribute__((address_space(3))) void*)(dst + (size_t)768 * 8),
            16, 0, 0);
}

// ------------------------------------------------------------- fused score+PV
// grid = nb*144; block = 256 (4 waves). BM=64 queries (4 py-rows x 16 px),
// BN=96 keys/iter, 24 iters. Wave w: score for q-tile w (both key halves),
// PV for n-quarter w over all 64 q (acc[4][9], 144 AGPR). Q tile in LDS.
// One counted-vmcnt barrier per iter (vmcnt(9): drains Ks DMA, keeps 9 V
// loads in flight). Register diet: Q in LDS, pa in 2x2 halves -> ~250 unified.
__launch_bounds__(256, 2)
__global__ void kfused3(const u16* __restrict__ xf16, const u16* __restrict__ rkl,
                        const u16* __restrict__ vtp, const float* __restrict__ invn,
                        float* __restrict__ Z, int b0, int nb) {
    __shared__ u16 Ks[2][6400];     // 25600 B: dbuf, 4 halo rows x [50 px][32 c] fp16
    __shared__ u16 Pl[2][6144];     // 24576 B: dbuf, [4 mtile][3 kb][16 m][32 kc]
    __shared__ float Ln[2304];      //  9216 B: invn for this batch
    __shared__ u16 Qs[6 * 18 * 32]; //  6912 B: Q tile rows pyb..pyb+5, px0..px0+17
    __shared__ float llds[4][16];   //   256 B  -> 66560 B total

    int tid = threadIdx.x;
    int w = tid >> 6, lane = tid & 63, l15 = lane & 15, quad = lane >> 4;
    int bi = blockIdx.x, brel, t;
    if (nb == 4) { brel = bi & 3; t = bi >> 2; }   // bi%8 fixes XCD: 1 batch per XCD
    else         { brel = 0; t = bi; }
    int b = b0 + brel;
    int px0 = (t % 6) * 16, pyb = (t / 6) * 4;     // 6 x-tiles x 24 y-groups = 144

    const u16* xb = xf16 + (size_t)b * 98 * 98 * 32;
    const u16* rb = rkl + (size_t)b * 50 * 50 * 32;
    const float* invb = invn + b * 2304;
    const u16* vw = vtp + (size_t)b * 576 * 2304 + (size_t)(w * 144 + l15) * 2304 + quad * 8;

    stage_ks(rb, Ks[0], tid);       // async; drained by the prologue barrier
    __builtin_amdgcn_sched_barrier(0);

    // invn -> LDS (once)
    for (int i = tid; i < 576; i += 256)
        ((float4*)Ln)[i] = ((const float4*)invb)[i];

    // Q tile -> LDS (once): 6 rows x 18 px x 32 c fp16 = 108 cells x 4 chunks
    for (int u = tid; u < 432; u += 256) {
        int cell = u >> 2, ch = u & 3;
        int r = cell / 18, p = cell % 18;
        *(short8*)&Qs[(r * 18 + p) * 32 + ch * 8] =
            *(const short8*)(xb + (((pyb + r) * 98) + (px0 + p)) * 32 + ch * 8);
    }

    f32x4 acc[36];
    #pragma unroll
    for (int i = 0; i < 36; i++) acc[i] = (f32x4)0.f;
    float lacc[4] = {0.f, 0.f, 0.f, 0.f};

    __syncthreads();   // prologue: full drain (Ks[0] DMA + Ln + Qs staged)

    short8 vv[9];

    for (int it = 0; it < 24; ++it) {
        int ly0 = it * 2;
        int cur = it & 1;

        // ---- 1. DMA next Ks (oldest VMEM of this iter — vmcnt(9) relies on it)
        if (it < 23) stage_ks(rb + (ly0 + 2) * 1600, Ks[cur ^ 1], tid);
        __builtin_amdgcn_sched_barrier(0);   // pin DMA-first issue order

        // ---- 2. V ks=0 loads (9; ride across the barrier into PV)
        const u16* vit = vw + it * 96;
        #pragma unroll
        for (int nt = 0; nt < 9; ++nt) vv[nt] = *(const short8*)(vit + (size_t)nt * 36864);

        // ---- 3+4. score + exp for both key halves of this wave's q-tile
        const u16* Kc = Ks[cur];
        u16* Pc = Pl[cur];
        #pragma unroll
        for (int kh = 0; kh < 2; ++kh) {
            f32x4 sf[3];
            #pragma unroll
            for (int i = 0; i < 3; i++) sf[i] = (f32x4)0.f;
            __builtin_amdgcn_s_setprio(1);
            #pragma unroll
            for (int ty = 0; ty < 3; ++ty)
                #pragma unroll
                for (int tx = 0; tx < 3; ++tx) {
                    half8 a = *(const half8*)&Qs[((w + ty) * 18 + (l15 + tx)) * 32 + quad * 8];
                    #pragma unroll
                    for (int lxo = 0; lxo < 3; ++lxo) {
                        half8 bb = *(const half8*)&Kc[(kh + ty) * 1600 + (lxo * 16 + l15 + tx) * 32 + quad * 8];
                        sf[lxo] = __builtin_amdgcn_mfma_f32_16x16x32_f16(a, bb, sf[lxo], 0, 0, 0);
                    }
                }
            __builtin_amdgcn_s_setprio(0);
            #pragma unroll
            for (int lxo = 0; lxo < 3; ++lxo) {
                float invs = Ln[(ly0 + kh) * 48 + lxo * 16 + l15];
                int k = kh * 48 + lxo * 16 + l15;
                int kb = k >> 5;
                int kc = (k & 31) ^ (quad << 3);   // XOR swizzle by quad (= m>>2)
                #pragma unroll
                for (int r = 0; r < 4; ++r) {
                    float p = __expf(sf[lxo][r] * invs);
                    u16 h = f2bf(p);
                    Pc[(w * 3 + kb) * 512 + (quad * 4 + r) * 32 + kc] = h;
                    lacc[r] += bf2f(h);   // l exactly as the PV MFMA sees P
                }
            }
        }

        // ---- 5. counted-vmcnt barrier: Pl visible (lgkm 0) + Ks DMA landed
        // (vmcnt<=9: the 9 newer vv loads may stay in flight).
        asm volatile("s_waitcnt vmcnt(9) lgkmcnt(0)" ::: "memory");
        __builtin_amdgcn_s_barrier();
        __builtin_amdgcn_sched_barrier(0);

        // ---- 6. PV: O[64, this wave's 144 cols] += P[64,96] @ V[96,144], bf16
        // pa loaded in 2x2 halves (8 regs live, not 16). vv[nt] reloaded for
        // the next ks right after its last use (2nd half), covered by MFMAs.
        const u16* Pr = Pl[cur];
        int pcol = l15 * 32 + ((quad ^ (l15 >> 2)) & 3) * 8;
        __builtin_amdgcn_s_setprio(1);
        #pragma unroll
        for (int ks = 0; ks < 3; ++ks) {
            short8 pa0 = *(const short8*)&Pr[(0 * 3 + ks) * 512 + pcol];
            short8 pa1 = *(const short8*)&Pr[(1 * 3 + ks) * 512 + pcol];
            #pragma unroll
            for (int nt = 0; nt < 9; ++nt) {
                short8 vn = vv[nt];
                acc[0 * 9 + nt] = __builtin_amdgcn_mfma_f32_16x16x32_bf16(pa0, vn, acc[0 * 9 + nt], 0, 0, 0);
                acc[1 * 9 + nt] = __builtin_amdgcn_mfma_f32_16x16x32_bf16(pa1, vn, acc[1 * 9 + nt], 0, 0, 0);
            }
            pa0 = *(const short8*)&Pr[(2 * 3 + ks) * 512 + pcol];
            pa1 = *(const short8*)&Pr[(3 * 3 + ks) * 512 + pcol];
            #pragma unroll
            for (int nt = 0; nt < 9; ++nt) {
                short8 vn = vv[nt];
                acc[2 * 9 + nt] = __builtin_amdgcn_mfma_f32_16x16x32_bf16(pa0, vn, acc[2 * 9 + nt], 0, 0, 0);
                acc[3 * 9 + nt] = __builtin_amdgcn_mfma_f32_16x16x32_bf16(pa1, vn, acc[3 * 9 + nt], 0, 0, 0);
                if (ks < 2)   // reload right after last use; covered by rest of phase
                    vv[nt] = *(const short8*)(vit + (size_t)nt * 36864 + (ks + 1) * 32);
            }
        }
        __builtin_amdgcn_s_setprio(0);
    }

    // ---- epilogue: reduce l over l15; share per-tile l via LDS; Z = O/(6l)
    #pragma unroll
    for (int r = 0; r < 4; ++r) {
        float v = lacc[r];
        v += __shfl_xor(v, 1);
        v += __shfl_xor(v, 2);
        v += __shfl_xor(v, 4);
        v += __shfl_xor(v, 8);
        lacc[r] = v;
    }
    if (l15 == 0) {
        #pragma unroll
        for (int r = 0; r < 4; ++r)
            llds[w][quad * 4 + r] = lacc[r];
    }
    __syncthreads();
    float* Zb = Z + (size_t)brel * 9216 * 576;
    #pragma unroll
    for (int mt = 0; mt < 4; ++mt) {
        #pragma unroll
        for (int r = 0; r < 4; ++r) {
            int q = (pyb + mt) * 96 + px0 + quad * 4 + r;
            float rl = 1.0f / (llds[mt][quad * 4 + r] * 6.0f);
            float* zr = Zb + (size_t)q * 576 + w * 144;
            #pragma unroll
            for (int nt = 0; nt < 9; ++nt)
                __builtin_nontemporal_store(acc[mt * 9 + nt][r] * rl, zr + nt * 16 + l15);
        }
    }
}

// ------------------------------------------------------------- gather (Z -> out)
__global__ void kgather(const float* __restrict__ Z, float* __restrict__ out, int b0) {
    __shared__ float zb[2 * 9 * 580];   // 41760 B
    int bi = blockIdx.x;                // nb*96*12
    int brel = bi / (96 * 12);
    int rem = bi % (96 * 12);
    int b = b0 + brel;
    int q = rem / 12, xt = rem % 12;
    int ox0 = xt * 16, p0 = ox0 >> 1;
    const float* Zb = Z + (size_t)brel * 9216 * 576;
    int tid = threadIdx.x;
    for (int id = tid; id < 2592; id += 256) {
        int pi = id / 1296, r2 = id % 1296;
        int pxi = r2 / 144, n4 = r2 % 144;
        int py = q + pi; if (py > 95) py = 95;
        int px = p0 + pxi; if (px > 95) px = 95;
        *(float4*)&zb[(pi * 9 + pxi) * 580 + n4 * 4] =
            *(const float4*)&Zb[(size_t)(py * 96 + px) * 576 + n4 * 4];
    }
    __syncthreads();
    int xi = tid & 15, cq = tid >> 4;
    int ox = ox0 + xi;
    bool oxv = ox <= 190;
    int ntx, txl[2], pxl[2];
    if (xi & 1) { ntx = 2; txl[0] = 0; pxl[0] = (xi + 1) >> 1; txl[1] = 2; pxl[1] = (xi - 1) >> 1; }
    else        { ntx = 1; txl[0] = 1; pxl[0] = xi >> 1; txl[1] = 1; pxl[1] = xi >> 1; }
    int oy0 = 2 * q;
    #pragma unroll
    for (int ck = 0; ck < 4; ++ck) {
        int c = cq + ck * 16;
        float v0 = 0.f, v1 = 0.f;
        for (int j = 0; j < ntx; ++j) {
            int tx = txl[j], pxi = pxl[j];
            v0 += zb[(0 * 9 + pxi) * 580 + (3 + tx) * 64 + c];
            v1 += zb[(1 * 9 + pxi) * 580 + (0 + tx) * 64 + c];
            v1 += zb[(0 * 9 + pxi) * 580 + (6 + tx) * 64 + c];
        }
        if (oxv) {
            float* o = out + (((size_t)(b * 64 + c) * 191 + oy0) * 191 + ox);
            *o = v0;
            if (q < 95) *(o + 191) = v1;
        }
    }
}

// --------------------------------------------------------------------- host
extern "C" void kernel_launch(void* const* d_in, const int* in_sizes, int n_in,
                              void* d_out, int out_size, void* d_ws, size_t ws_size,
                              hipStream_t stream) {
    const float* input = (const float*)d_in[0];
    const float* small = (const float*)d_in[1];
    const float* w1 = (const float*)d_in[2];
    const float* b1 = (const float*)d_in[3];
    const float* a1 = (const float*)d_in[4];
    const float* w2 = (const float*)d_in[5];
    const float* b2 = (const float*)d_in[6];
    const float* a2 = (const float*)d_in[7];
    const float* wa = (const float*)d_in[8];
    const float* ba = (const float*)d_in[9];
    const float* aa = (const float*)d_in[10];

    char* ws = (char*)d_ws;
    u16* xf16 = (u16*)(ws + 0);             //  2,458,624
    u16* rkl = (u16*)(ws + 2458624);        //    640,000
    float* ef = (float*)(ws + 3098624);     //  2,560,000
    u16* vtp = (u16*)(ws + 5658624);        // 10,616,832
    float* invn = (float*)(ws + 16275456);  //     36,864
    const size_t PREP = 16312320;
    float* Zbuf = (float*)(ws + PREP);      // nb*21,233,664
    float* out = (float*)d_out;

    int nb = (ws_size >= (size_t)101246976) ? 4 : 1;

    kzero<<<1024, 256, 0, stream>>>((float4*)ws, 5658624 / 16);   // halo'd arrays
    kmatch<<<384, 256, 0, stream>>>(input, w1, b1, a1, xf16);
    ksmall<<<192, 256, 0, stream>>>(small, wa, ba, aa, w2, b2, a2, ef, rkl);
    kinvnorm<<<36, 256, 0, stream>>>(rkl, invn);
    kvtp<<<2304, 256, 0, stream>>>(ef, vtp);

    for (int b0 = 0; b0 < 4; b0 += nb) {
        kfused3<<<nb * 144, 256, 0, stream>>>(xf16, rkl, vtp, invn, Zbuf, b0, nb);
        kgather<<<nb * 1152, 256, 0, stream>>>(Zbuf, out, b0);
    }
}